// Round 12
// baseline (233.066 us; speedup 1.0000x reference)
//
#include <hip/hip_runtime.h>

// x: (8, 160, 1024, 1) f32 ; W: (1, 7, 1, 32) f32
// y[n,h,w,c] = sum_k x[n,h,w+k-3] * W[k,c]   (SAME pad along w)
// per (n,w,c): m1 = max_h y, m2 = 2nd max, am = argmax_h
// out[n,h,w,c] = y[n,h,w,c] + (h==am ? m2 : m1)
//
// R11 resubmit (acquisition timeout): two-kernel split. Theory:
// single-kernel K=44-51us regardless of LDS strategy because stores are
// 1-2KB chunks strided 128KB apart (thread pins (w,c), iterates h)
// -> ~3.8 TB/s vs fill's 6.7 TB/s.
// A: pass1 only -> (m1,m2,am) tables in d_ws (3 MB).
// B: one block per (n,h), recompute conv (identical fmaf order ->
//    bitwise-equal y), add max-other, write 128 KB per block strictly
//    sequentially as float4 (the fill's pattern).

#define NW 1024
#define NH 160
#define NC 32

// ---------------- Kernel A: pass1 -> tables (R10 structure) ----------------
#define AWT   16
#define ALDSW 24

__global__ __launch_bounds__(256)
void pcc_pass1(const float* __restrict__ x,
               const float* __restrict__ Wf,
               float* __restrict__ m1t,
               float* __restrict__ m2t,
               int* __restrict__ amt) {
    __shared__ __align__(16) float xs[NH][ALDSW];

    const int n  = blockIdx.x >> 6;
    const int wt = blockIdx.x & 63;
    const int w0 = wt * AWT;
    const int tid = threadIdx.x;

    const float* xn = x + (size_t)n * NH * NW;
    for (int idx = tid; idx < NH * ALDSW; idx += 256) {
        int row = idx / ALDSW;
        int col = idx - row * ALDSW;
        int gw  = w0 - 3 + col;
        float v = 0.f;
        if (gw >= 0 && gw < NW) v = xn[row * NW + gw];
        xs[row][col] = v;
    }
    __syncthreads();

    const int c = tid & 31;
    const int t = tid >> 5;            // 0..7 -> w = w0+2t, +1

    float wg[7];
#pragma unroll
    for (int k = 0; k < 7; ++k) wg[k] = Wf[k * NC + c];

    float m1a = -INFINITY, m2a = -INFINITY;
    float m1b = -INFINITY, m2b = -INFINITY;
    int ama = 0, amb = 0;

#pragma unroll 4
    for (int h = 0; h < NH; ++h) {
        const float2* row = reinterpret_cast<const float2*>(&xs[h][2 * t]);
        float2 d0 = row[0], d1 = row[1], d2 = row[2], d3 = row[3];
        float f0 = d0.x, f1 = d0.y, f2 = d1.x, f3 = d1.y;
        float f4 = d2.x, f5 = d2.y, f6 = d3.x, f7 = d3.y;
        float ya = 0.f, yb = 0.f;
        ya = fmaf(f0, wg[0], ya); yb = fmaf(f1, wg[0], yb);
        ya = fmaf(f1, wg[1], ya); yb = fmaf(f2, wg[1], yb);
        ya = fmaf(f2, wg[2], ya); yb = fmaf(f3, wg[2], yb);
        ya = fmaf(f3, wg[3], ya); yb = fmaf(f4, wg[3], yb);
        ya = fmaf(f4, wg[4], ya); yb = fmaf(f5, wg[4], yb);
        ya = fmaf(f5, wg[5], ya); yb = fmaf(f6, wg[5], yb);
        ya = fmaf(f6, wg[6], ya); yb = fmaf(f7, wg[6], yb);
        bool ga = ya > m1a;
        m2a = ga ? m1a : fmaxf(m2a, ya);
        m1a = ga ? ya  : m1a;
        ama = ga ? h   : ama;
        bool gb = yb > m1b;
        m2b = gb ? m1b : fmaxf(m2b, yb);
        m1b = gb ? yb  : m1b;
        amb = gb ? h   : amb;
    }

    const int o = (n * NW + w0 + 2 * t) * NC + c;
    m1t[o] = m1a;  m1t[o + NC] = m1b;
    m2t[o] = m2a;  m2t[o + NC] = m2b;
    amt[o] = ama;  amt[o + NC] = amb;
}

// ---------------- Kernel B: emit, linear writes ----------------
__global__ __launch_bounds__(256)
void pcc_emit(const float* __restrict__ x,
              const float* __restrict__ Wf,
              const float* __restrict__ m1t,
              const float* __restrict__ m2t,
              const int* __restrict__ amt,
              float* __restrict__ out) {
    __shared__ __align__(16) float xr[1032];   // col j <-> w = j-3

    const int b = blockIdx.x;
    const int n = b / NH;
    const int h = b - n * NH;
    const int tid = threadIdx.x;

    const float* xrow = x + ((size_t)n * NH + h) * NW;
    for (int j = tid; j < NW + 6; j += 256) {
        int w = j - 3;
        xr[j] = (w >= 0 && w < NW) ? xrow[w] : 0.f;
    }
    __syncthreads();

    const int wl = tid >> 3;           // 0..31
    const int c0 = (tid & 7) * 4;      // 0,4,..,28

    float wg[7][4];
#pragma unroll
    for (int k = 0; k < 7; ++k) {
        float4 wv = *reinterpret_cast<const float4*>(&Wf[k * NC + c0]);
        wg[k][0] = wv.x; wg[k][1] = wv.y; wg[k][2] = wv.z; wg[k][3] = wv.w;
    }

    float* orow = out + ((size_t)(n * NH + h)) * NW * NC;
    const int tbase = n * NW * NC;

#pragma unroll 2
    for (int j = 0; j < 32; ++j) {
        const int w = j * 32 + wl;
        float f[7];
#pragma unroll
        for (int k = 0; k < 7; ++k) f[k] = xr[w + k];   // x[w-3+k]

        const int ti = tbase + w * NC + c0;
        float4 m1v = *reinterpret_cast<const float4*>(&m1t[ti]);
        float4 m2v = *reinterpret_cast<const float4*>(&m2t[ti]);
        int4   amv = *reinterpret_cast<const int4*>(&amt[ti]);

        float y0 = 0.f, y1 = 0.f, y2 = 0.f, y3 = 0.f;
#pragma unroll
        for (int k = 0; k < 7; ++k) {       // same fmaf order as pass1
            y0 = fmaf(f[k], wg[k][0], y0);
            y1 = fmaf(f[k], wg[k][1], y1);
            y2 = fmaf(f[k], wg[k][2], y2);
            y3 = fmaf(f[k], wg[k][3], y3);
        }
        float4 o;
        o.x = y0 + (h == amv.x ? m2v.x : m1v.x);
        o.y = y1 + (h == amv.y ? m2v.y : m1v.y);
        o.z = y2 + (h == amv.z ? m2v.z : m1v.z);
        o.w = y3 + (h == amv.w ? m2v.w : m1v.w);
        *reinterpret_cast<float4*>(&orow[(size_t)w * NC + c0]) = o;
    }
}

// ---------------- Fallback: R3 single-kernel (if ws too small) ----------------
__global__ __launch_bounds__(256)
void pcc_single(const float* __restrict__ x,
                const float* __restrict__ Wf,
                float* __restrict__ out) {
    __shared__ float xs[NH][14];
    const int n  = blockIdx.x >> 7;
    const int wt = blockIdx.x & 127;
    const int w0 = wt * 8;
    const int tid = threadIdx.x;
    const float* xn = x + (size_t)n * NH * NW;
    for (int idx = tid; idx < NH * 14; idx += 256) {
        int row = idx / 14;
        int col = idx - row * 14;
        int gw  = w0 - 3 + col;
        float v = 0.f;
        if (gw >= 0 && gw < NW) v = xn[row * NW + gw];
        xs[row][col] = v;
    }
    __syncthreads();
    const int c  = tid & 31;
    const int wl = tid >> 5;
    float wg[7];
#pragma unroll
    for (int k = 0; k < 7; ++k) wg[k] = Wf[k * NC + c];
    float m1 = -INFINITY, m2 = -INFINITY;
    int am = 0;
#pragma unroll 4
    for (int h = 0; h < NH; ++h) {
        float y = 0.f;
#pragma unroll
        for (int j = 0; j < 7; ++j) y = fmaf(xs[h][wl + j], wg[j], y);
        bool g = y > m1;
        m2 = g ? m1 : fmaxf(m2, y);
        m1 = g ? y  : m1;
        am = g ? h  : am;
    }
    float* obase = out + ((size_t)(n * NH) * NW + (w0 + wl)) * NC + c;
#pragma unroll 4
    for (int h = 0; h < NH; ++h) {
        float y = 0.f;
#pragma unroll
        for (int j = 0; j < 7; ++j) y = fmaf(xs[h][wl + j], wg[j], y);
        obase[(size_t)h * NW * NC] = y + (h == am ? m2 : m1);
    }
}

extern "C" void kernel_launch(void* const* d_in, const int* in_sizes, int n_in,
                              void* d_out, int out_size, void* d_ws, size_t ws_size,
                              hipStream_t stream) {
    const float* x  = (const float*)d_in[0];   // 8*160*1024
    const float* Wf = (const float*)d_in[1];   // 7*32
    float* out = (float*)d_out;                // 8*160*1024*32

    const size_t tbl = (size_t)8 * NW * NC;    // 262144 elems per table
    const size_t need = tbl * 4 * 3;           // 3 MB

    if (ws_size >= need) {
        float* m1t = (float*)d_ws;
        float* m2t = m1t + tbl;
        int*   amt = (int*)(m2t + tbl);
        pcc_pass1<<<dim3(8 * (NW / AWT)), dim3(256), 0, stream>>>(x, Wf, m1t, m2t, amt);
        pcc_emit <<<dim3(8 * NH),         dim3(256), 0, stream>>>(x, Wf, m1t, m2t, amt, out);
    } else {
        pcc_single<<<dim3(8 * (NW / 8)), dim3(256), 0, stream>>>(x, Wf, out);
    }
}